// Round 3
// baseline (447.346 us; speedup 1.0000x reference)
//
#include <hip/hip_runtime.h>
#include <hip/hip_bf16.h>

// ---------- helpers ----------
__device__ __forceinline__ float bf2f(unsigned short u) {
    return __uint_as_float(((unsigned int)u) << 16);
}
// runtime-dtype scalar load: bf=1 -> buffer is bf16, bf=0 -> float32
__device__ __forceinline__ float ldin(const void* p, int i, int bf) {
    return bf ? bf2f(((const unsigned short*)p)[i]) : ((const float*)p)[i];
}

#define N_NODES 512
#define C_FEAT  1024
#define NCLS 91
#define W1_LD 2052   // repn_w1 row length (2C+4)

// ---------- K0: detect input dtype ----------
// fp32 buffer: even-index ushorts are mantissa-low fragments -> decoding as
// bf16 yields huge/non-finite values w.p. ~1-1e-63 over 256 samples.
__global__ void k_detect(const void* __restrict__ feats, int* __restrict__ dmode) {
    if (threadIdx.x != 0 || blockIdx.x != 0) return;
    const unsigned short* u = (const unsigned short*)feats;
    int bf = 1;
    for (int i = 0; i < 512; i += 2) {
        float v = bf2f(u[i]);
        if (!isfinite(v) || fabsf(v) > 1.0e6f) { bf = 0; break; }
    }
    *dmode = bf;
}

// ---------- K1: p1 = feats @ wf1^T, p2 = feats @ wf2^T ----------
__global__ void k_p12(const void* __restrict__ feats,
                      const void* __restrict__ w1,
                      const int* __restrict__ dmode,
                      float* __restrict__ p1, float* __restrict__ p2) {
    int i = blockIdx.x, t = threadIdx.x; // 256 threads
    int bf = *dmode;
    __shared__ float fr[C_FEAT];
    if (bf) {
        const unsigned short* frow = (const unsigned short*)feats + i * C_FEAT;
        for (int c = t; c < C_FEAT; c += 256) fr[c] = bf2f(frow[c]);
    } else {
        const float* frow = (const float*)feats + i * C_FEAT;
        for (int c = t; c < C_FEAT; c += 256) fr[c] = frow[c];
    }
    __syncthreads();
    float a1 = 0.f, a2 = 0.f;
    if (bf) {
        const unsigned short* wrow = (const unsigned short*)w1 + t * W1_LD;
        for (int c = 0; c < C_FEAT; c += 4) {
            ushort4 u1 = *(const ushort4*)(wrow + c);
            ushort4 u2 = *(const ushort4*)(wrow + C_FEAT + c);
            a1 += fr[c] * bf2f(u1.x) + fr[c + 1] * bf2f(u1.y) + fr[c + 2] * bf2f(u1.z) + fr[c + 3] * bf2f(u1.w);
            a2 += fr[c] * bf2f(u2.x) + fr[c + 1] * bf2f(u2.y) + fr[c + 2] * bf2f(u2.z) + fr[c + 3] * bf2f(u2.w);
        }
    } else {
        const float* wrow = (const float*)w1 + t * W1_LD;
        for (int c = 0; c < C_FEAT; c += 4) {
            float4 u1 = *(const float4*)(wrow + c);
            float4 u2 = *(const float4*)(wrow + C_FEAT + c);
            a1 += fr[c] * u1.x + fr[c + 1] * u1.y + fr[c + 2] * u1.z + fr[c + 3] * u1.w;
            a2 += fr[c] * u2.x + fr[c + 1] * u2.y + fr[c + 2] * u2.z + fr[c + 3] * u2.w;
        }
    }
    p1[i * 256 + t] = a1;
    p2[i * 256 + t] = a2;
}

// ---------- K2: rel[i,j] ----------
__global__ void k_rel(const float* __restrict__ p1, const float* __restrict__ p2,
                      const void* __restrict__ w1,   // wg cols 2048..2051
                      const void* __restrict__ b1,
                      const void* __restrict__ w2,
                      const void* __restrict__ b2,
                      const void* __restrict__ boxes,
                      const int* __restrict__ dmode,
                      float* __restrict__ relf, float* __restrict__ rel_out) {
    int i = blockIdx.y, jb = blockIdx.x, t = threadIdx.x; // 256 threads
    int j = jb * 256 + t;
    int bf = *dmode;
    __shared__ float s1[256], sw2[256], swg[256][4], bi[4];
    s1[t] = p1[i * 256 + t] + ldin(b1, t, bf);
    sw2[t] = ldin(w2, t, bf);
    swg[t][0] = ldin(w1, t * W1_LD + 2048, bf);
    swg[t][1] = ldin(w1, t * W1_LD + 2049, bf);
    swg[t][2] = ldin(w1, t * W1_LD + 2050, bf);
    swg[t][3] = ldin(w1, t * W1_LD + 2051, bf);
    if (t < 4) bi[t] = ldin(boxes, i * 4 + t, bf);
    __syncthreads();
    float g0 = fabsf(bi[0] - ldin(boxes, j * 4 + 0, bf));
    float g1 = fabsf(bi[1] - ldin(boxes, j * 4 + 1, bf));
    float g2 = fabsf(bi[2] - ldin(boxes, j * 4 + 2, bf));
    float g3 = fabsf(bi[3] - ldin(boxes, j * 4 + 3, bf));
    const float4* p2r = (const float4*)(p2 + j * 256);
    float acc = 0.f;
    for (int h4 = 0; h4 < 64; ++h4) {
        float4 pv = p2r[h4];
        int h = h4 * 4;
        float t0 = s1[h]     + pv.x + g0 * swg[h][0]     + g1 * swg[h][1]     + g2 * swg[h][2]     + g3 * swg[h][3];
        float t1 = s1[h + 1] + pv.y + g0 * swg[h + 1][0] + g1 * swg[h + 1][1] + g2 * swg[h + 1][2] + g3 * swg[h + 1][3];
        float t2 = s1[h + 2] + pv.z + g0 * swg[h + 2][0] + g1 * swg[h + 2][1] + g2 * swg[h + 2][2] + g3 * swg[h + 2][3];
        float t3 = s1[h + 3] + pv.w + g0 * swg[h + 3][0] + g1 * swg[h + 3][1] + g2 * swg[h + 3][2] + g3 * swg[h + 3][3];
        acc += sw2[h] * fmaxf(t0, 0.f) + sw2[h + 1] * fmaxf(t1, 0.f)
             + sw2[h + 2] * fmaxf(t2, 0.f) + sw2[h + 3] * fmaxf(t3, 0.f);
    }
    float r = acc + ldin(b2, 0, bf);
    relf[i * 512 + j] = r;
    rel_out[i * 512 + j] = r;
}

// ---------- K3: per-row top-(k+1), drop first; count in-degrees ----------
__global__ void k_topk(const float* __restrict__ relf, const int* __restrict__ kp,
                       int* __restrict__ nbrs, int* __restrict__ count) {
    int i = blockIdx.x, lane = threadIdx.x; // 64 threads = 1 wave
    int k = *kp;
    float v[8]; int ids[8];
    for (int q = 0; q < 8; ++q) {
        int j = lane + 64 * q;
        v[q] = relf[i * 512 + j];
        ids[q] = j;
    }
    for (int pick = 0; pick < k + 1; ++pick) {
        float bv = -INFINITY; int bidx = 1 << 30;
        for (int q = 0; q < 8; ++q) {
            if (v[q] > bv || (v[q] == bv && ids[q] < bidx)) { bv = v[q]; bidx = ids[q]; }
        }
        for (int off = 32; off > 0; off >>= 1) {
            float ov = __shfl_down(bv, off);
            int oi = __shfl_down(bidx, off);
            if (ov > bv || (ov == bv && oi < bidx)) { bv = ov; bidx = oi; }
        }
        bv = __shfl(bv, 0); bidx = __shfl(bidx, 0);
        if (pick >= 1 && lane == 0) {
            nbrs[i * 8 + (pick - 1)] = bidx;
            atomicAdd(&count[bidx], 1);
        }
        for (int q = 0; q < 8; ++q) if (ids[q] == bidx) v[q] = -INFINITY;
    }
    if (lane == 0) atomicAdd(&count[i], 1); // self loop
}

// ---------- K4: exclusive scan ----------
__global__ void k_scan(const int* __restrict__ count, int* __restrict__ offs) {
    __shared__ int s[512];
    int t = threadIdx.x; // 512 threads, 1 block
    s[t] = count[t];
    __syncthreads();
    for (int off = 1; off < 512; off <<= 1) {
        int v = (t >= off) ? s[t - off] : 0;
        __syncthreads();
        s[t] += v;
        __syncthreads();
    }
    offs[t + 1] = s[t];
    if (t == 0) offs[0] = 0;
}

// ---------- K5: fill in-edge lists ----------
__global__ void k_fill(const int* __restrict__ nbrs, const int* __restrict__ kp,
                       const int* __restrict__ offs, int* __restrict__ cursor,
                       int* __restrict__ inlist) {
    int i = blockIdx.x * blockDim.x + threadIdx.x;
    if (i >= N_NODES) return;
    int k = *kp;
    for (int q = 0; q < k; ++q) {
        int d = nbrs[i * 8 + q] & 511;
        int pos = atomicAdd(&cursor[d], 1);
        inlist[offs[d] + pos] = i;
    }
    int pos = atomicAdd(&cursor[i], 1);
    inlist[offs[i] + pos] = i;
}

// ---------- K6: GAT1 GEMM  hX = [feats|geom] @ gat1_w ----------
__global__ void k_gat1(const void* __restrict__ feats,
                       const void* __restrict__ boxes,
                       const void* __restrict__ W,
                       const int* __restrict__ dmode,
                       float* __restrict__ hX) {
    int nb = blockIdx.x, t = threadIdx.x; // 128 blocks x 256 threads
    int bf = *dmode;
    __shared__ float xs[4][1028];
    for (int idx = t; idx < 4 * 1028; idx += 256) {
        int nn = idx / 1028, c = idx % 1028;
        int node = nb * 4 + nn;
        float v;
        if (c < 1024) v = ldin(feats, node * C_FEAT + c, bf);
        else {
            float b0 = ldin(boxes, node * 4 + 0, bf) / 800.f;
            float b1v = ldin(boxes, node * 4 + 1, bf) / 800.f;
            float b2v = ldin(boxes, node * 4 + 2, bf) / 800.f;
            float b3v = ldin(boxes, node * 4 + 3, bf) / 800.f;
            float g[4] = { b0, b1v, b2v - b0, b3v - b1v };
            v = g[c - 1024];
        }
        xs[nn][c] = v;
    }
    __syncthreads();
    float acc[4][4] = {};
    if (bf) {
        const unsigned short* Wu = (const unsigned short*)W;
        for (int c = 0; c < 1028; ++c) {
            const unsigned short* wr = Wu + c * 1024;
            float w0 = bf2f(wr[t]);
            float w1 = bf2f(wr[256 + t]);
            float w2 = bf2f(wr[512 + t]);
            float w3 = bf2f(wr[768 + t]);
            for (int nn = 0; nn < 4; ++nn) {
                float xv = xs[nn][c];
                acc[nn][0] += xv * w0; acc[nn][1] += xv * w1;
                acc[nn][2] += xv * w2; acc[nn][3] += xv * w3;
            }
        }
    } else {
        const float* Wf = (const float*)W;
        for (int c = 0; c < 1028; ++c) {
            const float* wr = Wf + c * 1024;
            float w0 = wr[t];
            float w1 = wr[256 + t];
            float w2 = wr[512 + t];
            float w3 = wr[768 + t];
            for (int nn = 0; nn < 4; ++nn) {
                float xv = xs[nn][c];
                acc[nn][0] += xv * w0; acc[nn][1] += xv * w1;
                acc[nn][2] += xv * w2; acc[nn][3] += xv * w3;
            }
        }
    }
    for (int nn = 0; nn < 4; ++nn)
        for (int q = 0; q < 4; ++q)
            hX[(nb * 4 + nn) * 1024 + q * 256 + t] = acc[nn][q];
}

// ---------- K7: a_s / a_d per node, per head ----------
__global__ void k_asd1(const float* __restrict__ hX,
                       const void* __restrict__ asrc,
                       const void* __restrict__ adst,
                       const int* __restrict__ dmode,
                       float* __restrict__ a_s, float* __restrict__ a_d) {
    int n = blockIdx.x, t = threadIdx.x; // 512 blocks x 256 threads
    int bf = *dmode;
    __shared__ float red[256];
    float ps[4], pd[4];
    for (int q = 0; q < 4; ++q) {
        float v = hX[n * 1024 + q * 256 + t];
        ps[q] = v * ldin(asrc, q * 256 + t, bf);
        pd[q] = v * ldin(adst, q * 256 + t, bf);
    }
    for (int q = 0; q < 4; ++q) {
        red[t] = ps[q]; __syncthreads();
        for (int s = 128; s > 0; s >>= 1) { if (t < s) red[t] += red[t + s]; __syncthreads(); }
        if (t == 0) a_s[n * 4 + q] = red[0];
        __syncthreads();
        red[t] = pd[q]; __syncthreads();
        for (int s = 128; s > 0; s >>= 1) { if (t < s) red[t] += red[t + s]; __syncthreads(); }
        if (t == 0) a_d[n * 4 + q] = red[0];
        __syncthreads();
    }
}

// ---------- K8: GAT1 per-dst softmax + aggregate + bias + relu ----------
__global__ void k_aggr1(const float* __restrict__ hX,
                        const float* __restrict__ a_s, const float* __restrict__ a_d,
                        const int* __restrict__ offs, const int* __restrict__ inlist,
                        const void* __restrict__ bias,
                        const int* __restrict__ dmode,
                        float* __restrict__ h1) {
    int n = blockIdx.x, t = threadIdx.x; // 512 blocks x 256 threads
    int bf = *dmode;
    int beg = offs[n], deg = offs[n + 1] - beg;
    if (deg > 513) deg = 513;
    __shared__ int srcs[520];
    __shared__ float alpha[520][4];
    __shared__ float sm[4];
    for (int e = t; e < deg; e += 256) srcs[e] = inlist[beg + e] & 511;
    __syncthreads();
    for (int idx = t; idx < deg * 4; idx += 256) {
        int e = idx >> 2, q = idx & 3;
        float sc = a_s[srcs[e] * 4 + q] + a_d[n * 4 + q];
        alpha[e][q] = (sc >= 0.f) ? sc : 0.2f * sc;
    }
    __syncthreads();
    if (t < 4) {
        float m = -INFINITY;
        for (int e = 0; e < deg; ++e) m = fmaxf(m, alpha[e][t]);
        if (!isfinite(m)) m = 0.f;
        float s = 0.f;
        for (int e = 0; e < deg; ++e) { float ex = expf(alpha[e][t] - m); alpha[e][t] = ex; s += ex; }
        sm[t] = s + 1e-16f;
    }
    __syncthreads();
    for (int idx = t; idx < deg * 4; idx += 256) {
        int e = idx >> 2, q = idx & 3;
        alpha[e][q] /= sm[q];
    }
    __syncthreads();
    for (int q = 0; q < 4; ++q) {
        float acc = 0.f;
        for (int e = 0; e < deg; ++e) acc += alpha[e][q] * hX[srcs[e] * 1024 + q * 256 + t];
        float o = acc + ldin(bias, q * 256 + t, bf);
        h1[n * 1024 + q * 256 + t] = fmaxf(o, 0.f);
    }
}

// ---------- K9: GAT2 GEMM + per-node a_s2 / a_d2 ----------
__global__ void k_gat2(const float* __restrict__ h1,
                       const void* __restrict__ W,
                       const void* __restrict__ asrc,
                       const void* __restrict__ adst,
                       const int* __restrict__ dmode,
                       float* __restrict__ h2, float* __restrict__ a_s2, float* __restrict__ a_d2) {
    int n = blockIdx.x, t = threadIdx.x; // 512 blocks x 128 threads
    int bf = *dmode;
    __shared__ float xs[1024];
    __shared__ float red[128];
    for (int c = t; c < 1024; c += 128) xs[c] = h1[n * 1024 + c];
    __syncthreads();
    float acc = 0.f;
    if (t < NCLS) {
        if (bf) {
            const unsigned short* Wu = (const unsigned short*)W;
            for (int c = 0; c < 1024; ++c) acc += xs[c] * bf2f(Wu[c * NCLS + t]);
        } else {
            const float* Wf = (const float*)W;
            for (int c = 0; c < 1024; ++c) acc += xs[c] * Wf[c * NCLS + t];
        }
    }
    float ps = 0.f, pd = 0.f;
    if (t < NCLS) {
        ps = acc * ldin(asrc, t, bf);
        pd = acc * ldin(adst, t, bf);
        h2[n * NCLS + t] = acc;
    }
    red[t] = (t < NCLS) ? ps : 0.f; __syncthreads();
    for (int s = 64; s > 0; s >>= 1) { if (t < s) red[t] += red[t + s]; __syncthreads(); }
    if (t == 0) a_s2[n] = red[0];
    __syncthreads();
    red[t] = (t < NCLS) ? pd : 0.f; __syncthreads();
    for (int s = 64; s > 0; s >>= 1) { if (t < s) red[t] += red[t + s]; __syncthreads(); }
    if (t == 0) a_d2[n] = red[0];
}

// ---------- K10: GAT2 aggregate -> logits + softmax probs ----------
__global__ void k_aggr2(const float* __restrict__ h2,
                        const float* __restrict__ a_s2, const float* __restrict__ a_d2,
                        const int* __restrict__ offs, const int* __restrict__ inlist,
                        const void* __restrict__ bias,
                        const int* __restrict__ dmode,
                        float* __restrict__ logits_out,
                        float* __restrict__ probs_out) {
    int n = blockIdx.x, t = threadIdx.x; // 512 blocks x 128 threads
    int bf = *dmode;
    int beg = offs[n], deg = offs[n + 1] - beg;
    if (deg > 513) deg = 513;
    __shared__ int srcs[520];
    __shared__ float alpha[520];
    __shared__ float red[128];
    __shared__ float smden;
    for (int e = t; e < deg; e += 128) {
        int s = inlist[beg + e] & 511;
        srcs[e] = s;
        float sc = a_s2[s] + a_d2[n];
        alpha[e] = (sc >= 0.f) ? sc : 0.2f * sc;
    }
    __syncthreads();
    if (t == 0) {
        float m = -INFINITY;
        for (int e = 0; e < deg; ++e) m = fmaxf(m, alpha[e]);
        if (!isfinite(m)) m = 0.f;
        float s = 0.f;
        for (int e = 0; e < deg; ++e) { float ex = expf(alpha[e] - m); alpha[e] = ex; s += ex; }
        smden = s + 1e-16f;
    }
    __syncthreads();
    float logit = 0.f;
    if (t < NCLS) {
        float acc = 0.f;
        for (int e = 0; e < deg; ++e) acc += alpha[e] * h2[srcs[e] * NCLS + t];
        acc /= smden;
        logit = acc + ldin(bias, t, bf);
        logits_out[n * NCLS + t] = logit;
    }
    red[t] = (t < NCLS) ? logit : -INFINITY; __syncthreads();
    for (int s = 64; s > 0; s >>= 1) { if (t < s) red[t] = fmaxf(red[t], red[t + s]); __syncthreads(); }
    float mx = red[0];
    __syncthreads();
    float ex = (t < NCLS) ? expf(logit - mx) : 0.f;
    red[t] = ex; __syncthreads();
    for (int s = 64; s > 0; s >>= 1) { if (t < s) red[t] += red[t + s]; __syncthreads(); }
    float inv = 1.f / red[0];
    if (t < NCLS) probs_out[n * NCLS + t] = ex * inv;
}

// ---------- launch ----------
extern "C" void kernel_launch(void* const* d_in, const int* in_sizes, int n_in,
                              void* d_out, int out_size, void* d_ws, size_t ws_size,
                              hipStream_t stream) {
    const void* feats   = d_in[0];
    const void* boxes   = d_in[1];
    const void* repn_w1 = d_in[2];
    const void* repn_b1 = d_in[3];
    const void* repn_w2 = d_in[4];
    const void* repn_b2 = d_in[5];
    const void* gat1_w    = d_in[6];
    const void* gat1_asrc = d_in[7];
    const void* gat1_adst = d_in[8];
    const void* gat1_b    = d_in[9];
    const void* gat2_w    = d_in[10];
    const void* gat2_asrc = d_in[11];
    const void* gat2_adst = d_in[12];
    const void* gat2_b    = d_in[13];
    const int* kp = (const int*)d_in[14];

    float* out = (float*)d_out;
    float* logits_out = out;                    // 512*91
    float* probs_out  = out + 512 * NCLS;       // 512*91
    float* rel_out    = out + 2 * 512 * NCLS;   // 512*512

    // Workspace layout (floats), hX aliased over dead p1/p2/relf:
    float* wsf = (float*)d_ws;
    float* p1   = wsf;                        // [0, 131072)
    float* p2   = wsf + 131072;               // [131072, 262144)
    float* relf = wsf + 262144;               // [262144, 524288)  dead after k_topk
    float* hX   = wsf;                        // [0, 524288)       alias, written at k_gat1
    float* h1   = wsf + 524288;               // [524288, 1048576)
    float* h2   = wsf + 1048576;              // 46592 (pad to 47104)
    float* a_s1 = wsf + 1095680;              // 2048
    float* a_d1 = a_s1 + 2048;                // 2048
    float* a_s2 = a_d1 + 2048;                // 512
    float* a_d2 = a_s2 + 512;                 // 512  -> ends at 1100800
    int* iw     = (int*)(wsf + 1100800);
    int* nbrs   = iw;                         // 4096
    int* count  = nbrs + 4096;                // 512
    int* cursor = count + 512;                // 512
    int* offs   = cursor + 512;               // 520
    int* inlist = offs + 520;                 // 4096
    int* dmode  = inlist + 4096;              // 1

    hipMemsetAsync(count, 0, 1024 * sizeof(int), stream); // count+cursor

    k_detect<<<dim3(1), dim3(64), 0, stream>>>(feats, dmode);
    k_p12<<<dim3(512), dim3(256), 0, stream>>>(feats, repn_w1, dmode, p1, p2);
    k_rel<<<dim3(2, 512), dim3(256), 0, stream>>>(p1, p2, repn_w1, repn_b1, repn_w2,
                                                  repn_b2, boxes, dmode, relf, rel_out);
    k_topk<<<dim3(512), dim3(64), 0, stream>>>(relf, kp, nbrs, count);
    k_scan<<<dim3(1), dim3(512), 0, stream>>>(count, offs);
    k_fill<<<dim3(2), dim3(256), 0, stream>>>(nbrs, kp, offs, cursor, inlist);
    k_gat1<<<dim3(128), dim3(256), 0, stream>>>(feats, boxes, gat1_w, dmode, hX);
    k_asd1<<<dim3(512), dim3(256), 0, stream>>>(hX, gat1_asrc, gat1_adst, dmode, a_s1, a_d1);
    k_aggr1<<<dim3(512), dim3(256), 0, stream>>>(hX, a_s1, a_d1, offs, inlist, gat1_b, dmode, h1);
    k_gat2<<<dim3(512), dim3(128), 0, stream>>>(h1, gat2_w, gat2_asrc, gat2_adst, dmode,
                                                h2, a_s2, a_d2);
    k_aggr2<<<dim3(512), dim3(128), 0, stream>>>(h2, a_s2, a_d2, offs, inlist, gat2_b, dmode,
                                                 logits_out, probs_out);
}

// Round 4
// 308.452 us; speedup vs baseline: 1.4503x; 1.4503x over previous
//
#include <hip/hip_runtime.h>

// Inputs and outputs are float32 (proven R1: bf16-interpretation -> NaN;
// R3: fp32 path passed with absmax 0.0625).

#define N_NODES 512
#define C_FEAT  1024
#define NCLS 91
#define W1_LD 2052   // repn_w1 row length (2C+4)

// ---------- K1: p[i][r] = feats[i] . Wcomb[r],  Wcomb rows 0..255 = wf1, 256..511 = wf2 ----------
// 64x64 tile, BK=32, 256 threads, 4x4 micro-tile.
__global__ __launch_bounds__(256) void k_p12(const float* __restrict__ feats,
                                             const float* __restrict__ w1f,
                                             float* __restrict__ p) {
    int r0 = blockIdx.x * 64, i0 = blockIdx.y * 64;
    int tid = threadIdx.x, tx = tid & 15, ty = tid >> 4;
    __shared__ float As[32 * 64];  // [k][i]
    __shared__ float Bs[32 * 64];  // [k][r]
    float acc[4][4] = {};
    for (int kt = 0; kt < 32; ++kt) {
        int kbase = kt * 32;
#pragma unroll
        for (int q = 0; q < 2; ++q) {
            int L = tid * 2 + q;
            int rl = L >> 3, kb = (L & 7) * 4;
            float4 av = *(const float4*)(feats + (i0 + rl) * 1024 + kbase + kb);
            As[(kb + 0) * 64 + rl] = av.x; As[(kb + 1) * 64 + rl] = av.y;
            As[(kb + 2) * 64 + rl] = av.z; As[(kb + 3) * 64 + rl] = av.w;
            int r = r0 + rl;
            const float* wr = w1f + (r < 256 ? r * W1_LD : (r - 256) * W1_LD + 1024);
            float4 bv = *(const float4*)(wr + kbase + kb);
            Bs[(kb + 0) * 64 + rl] = bv.x; Bs[(kb + 1) * 64 + rl] = bv.y;
            Bs[(kb + 2) * 64 + rl] = bv.z; Bs[(kb + 3) * 64 + rl] = bv.w;
        }
        __syncthreads();
#pragma unroll
        for (int k = 0; k < 32; ++k) {
            float4 a4 = *(const float4*)(As + k * 64 + ty * 4);
            float4 b4 = *(const float4*)(Bs + k * 64 + tx * 4);
            acc[0][0] = fmaf(a4.x, b4.x, acc[0][0]); acc[0][1] = fmaf(a4.x, b4.y, acc[0][1]);
            acc[0][2] = fmaf(a4.x, b4.z, acc[0][2]); acc[0][3] = fmaf(a4.x, b4.w, acc[0][3]);
            acc[1][0] = fmaf(a4.y, b4.x, acc[1][0]); acc[1][1] = fmaf(a4.y, b4.y, acc[1][1]);
            acc[1][2] = fmaf(a4.y, b4.z, acc[1][2]); acc[1][3] = fmaf(a4.y, b4.w, acc[1][3]);
            acc[2][0] = fmaf(a4.z, b4.x, acc[2][0]); acc[2][1] = fmaf(a4.z, b4.y, acc[2][1]);
            acc[2][2] = fmaf(a4.z, b4.z, acc[2][2]); acc[2][3] = fmaf(a4.z, b4.w, acc[2][3]);
            acc[3][0] = fmaf(a4.w, b4.x, acc[3][0]); acc[3][1] = fmaf(a4.w, b4.y, acc[3][1]);
            acc[3][2] = fmaf(a4.w, b4.z, acc[3][2]); acc[3][3] = fmaf(a4.w, b4.w, acc[3][3]);
        }
        __syncthreads();
    }
#pragma unroll
    for (int ii = 0; ii < 4; ++ii) {
        float4 o = make_float4(acc[ii][0], acc[ii][1], acc[ii][2], acc[ii][3]);
        *(float4*)(p + (i0 + ty * 4 + ii) * 512 + r0 + tx * 4) = o;
    }
}

// ---------- K2: rel[i][j] — 16i x 64j tile, h-chunked ----------
__global__ __launch_bounds__(256) void k_rel(const float* __restrict__ p,
                                             const float* __restrict__ w1f,
                                             const float* __restrict__ b1f,
                                             const float* __restrict__ w2f,
                                             const float* __restrict__ b2f,
                                             const float* __restrict__ boxesf,
                                             float* __restrict__ rel_out) {
    int j0 = blockIdx.x * 64, i0 = blockIdx.y * 16;
    int tid = threadIdx.x, tx = tid & 63, ty = tid >> 6;
    __shared__ float As1[32 * 16];  // [h][i]: p1 + b1
    __shared__ float Bs[32 * 64];   // [h][j]: p2
    __shared__ float Awg[32 * 4];
    __shared__ float Aw2[32];
    float4 bj = *(const float4*)(boxesf + (j0 + tx) * 4);
    float g[4][4];
#pragma unroll
    for (int s = 0; s < 4; ++s) {
        float4 bi = *(const float4*)(boxesf + (i0 + ty * 4 + s) * 4);
        g[s][0] = fabsf(bi.x - bj.x); g[s][1] = fabsf(bi.y - bj.y);
        g[s][2] = fabsf(bi.z - bj.z); g[s][3] = fabsf(bi.w - bj.w);
    }
    float acc[4] = {0.f, 0.f, 0.f, 0.f};
    for (int ch = 0; ch < 8; ++ch) {
        if (tid < 128) {
            int il = tid >> 3, hb = (tid & 7) * 4;
            float4 v = *(const float4*)(p + (i0 + il) * 512 + ch * 32 + hb);
            float4 b = *(const float4*)(b1f + ch * 32 + hb);
            As1[(hb + 0) * 16 + il] = v.x + b.x; As1[(hb + 1) * 16 + il] = v.y + b.y;
            As1[(hb + 2) * 16 + il] = v.z + b.z; As1[(hb + 3) * 16 + il] = v.w + b.w;
        }
#pragma unroll
        for (int q = 0; q < 2; ++q) {
            int L = tid * 2 + q;
            int jl = L >> 3, hb = (L & 7) * 4;
            float4 v = *(const float4*)(p + (j0 + jl) * 512 + 256 + ch * 32 + hb);
            Bs[(hb + 0) * 64 + jl] = v.x; Bs[(hb + 1) * 64 + jl] = v.y;
            Bs[(hb + 2) * 64 + jl] = v.z; Bs[(hb + 3) * 64 + jl] = v.w;
        }
        if (tid < 32) {
            int hg = ch * 32 + tid;
            float4 wg = *(const float4*)(w1f + hg * W1_LD + 2048);
            *(float4*)(Awg + tid * 4) = wg;
            Aw2[tid] = w2f[hg];
        }
        __syncthreads();
#pragma unroll
        for (int hh = 0; hh < 32; ++hh) {
            float4 wg = *(const float4*)(Awg + hh * 4);
            float w2v = Aw2[hh];
            float p2v = Bs[hh * 64 + tx];
            float4 s4 = *(const float4*)(As1 + hh * 16 + ty * 4);
            float t0 = s4.x + p2v;
            t0 = fmaf(g[0][0], wg.x, t0); t0 = fmaf(g[0][1], wg.y, t0);
            t0 = fmaf(g[0][2], wg.z, t0); t0 = fmaf(g[0][3], wg.w, t0);
            acc[0] = fmaf(w2v, fmaxf(t0, 0.f), acc[0]);
            float t1 = s4.y + p2v;
            t1 = fmaf(g[1][0], wg.x, t1); t1 = fmaf(g[1][1], wg.y, t1);
            t1 = fmaf(g[1][2], wg.z, t1); t1 = fmaf(g[1][3], wg.w, t1);
            acc[1] = fmaf(w2v, fmaxf(t1, 0.f), acc[1]);
            float t2 = s4.z + p2v;
            t2 = fmaf(g[2][0], wg.x, t2); t2 = fmaf(g[2][1], wg.y, t2);
            t2 = fmaf(g[2][2], wg.z, t2); t2 = fmaf(g[2][3], wg.w, t2);
            acc[2] = fmaf(w2v, fmaxf(t2, 0.f), acc[2]);
            float t3 = s4.w + p2v;
            t3 = fmaf(g[3][0], wg.x, t3); t3 = fmaf(g[3][1], wg.y, t3);
            t3 = fmaf(g[3][2], wg.z, t3); t3 = fmaf(g[3][3], wg.w, t3);
            acc[3] = fmaf(w2v, fmaxf(t3, 0.f), acc[3]);
        }
        __syncthreads();
    }
    float b2v = b2f[0];
#pragma unroll
    for (int s = 0; s < 4; ++s)
        rel_out[(i0 + ty * 4 + s) * 512 + j0 + tx] = acc[s] + b2v;
}

// ---------- K3: per-row top-(k+1), drop first; count in-degrees ----------
__global__ void k_topk(const float* __restrict__ relf, const int* __restrict__ kp,
                       int* __restrict__ nbrs, int* __restrict__ count) {
    int i = blockIdx.x, lane = threadIdx.x; // 64 threads = 1 wave
    int k = *kp;
    float v[8]; int ids[8];
    for (int q = 0; q < 8; ++q) {
        int j = lane + 64 * q;
        v[q] = relf[i * 512 + j];
        ids[q] = j;
    }
    for (int pick = 0; pick < k + 1; ++pick) {
        float bv = -INFINITY; int bidx = 1 << 30;
        for (int q = 0; q < 8; ++q) {
            if (v[q] > bv || (v[q] == bv && ids[q] < bidx)) { bv = v[q]; bidx = ids[q]; }
        }
        for (int off = 32; off > 0; off >>= 1) {
            float ov = __shfl_down(bv, off);
            int oi = __shfl_down(bidx, off);
            if (ov > bv || (ov == bv && oi < bidx)) { bv = ov; bidx = oi; }
        }
        bv = __shfl(bv, 0); bidx = __shfl(bidx, 0);
        if (pick >= 1 && lane == 0) {
            nbrs[i * 8 + (pick - 1)] = bidx;
            atomicAdd(&count[bidx], 1);
        }
        for (int q = 0; q < 8; ++q) if (ids[q] == bidx) v[q] = -INFINITY;
    }
    if (lane == 0) atomicAdd(&count[i], 1); // self loop
}

// ---------- K4: exclusive scan ----------
__global__ void k_scan(const int* __restrict__ count, int* __restrict__ offs) {
    __shared__ int s[512];
    int t = threadIdx.x;
    s[t] = count[t];
    __syncthreads();
    for (int off = 1; off < 512; off <<= 1) {
        int v = (t >= off) ? s[t - off] : 0;
        __syncthreads();
        s[t] += v;
        __syncthreads();
    }
    offs[t + 1] = s[t];
    if (t == 0) offs[0] = 0;
}

// ---------- K5: fill in-edge lists ----------
__global__ void k_fill(const int* __restrict__ nbrs, const int* __restrict__ kp,
                       const int* __restrict__ offs, int* __restrict__ cursor,
                       int* __restrict__ inlist) {
    int i = blockIdx.x * blockDim.x + threadIdx.x;
    if (i >= N_NODES) return;
    int k = *kp;
    for (int q = 0; q < k; ++q) {
        int d = nbrs[i * 8 + q] & 511;
        int pos = atomicAdd(&cursor[d], 1);
        inlist[offs[d] + pos] = i;
    }
    int pos = atomicAdd(&cursor[i], 1);
    inlist[offs[i] + pos] = i;
}

// ---------- K6: GAT1 GEMM  hX = [feats|geom] @ gat1_w  (M=512,K=1028,N=1024) ----------
__global__ __launch_bounds__(256) void k_gat1(const float* __restrict__ feats,
                                              const float* __restrict__ boxesf,
                                              const float* __restrict__ Wg,
                                              float* __restrict__ hX) {
    int n0 = blockIdx.x * 64, i0 = blockIdx.y * 64;
    int tid = threadIdx.x, tx = tid & 15, ty = tid >> 4;
    __shared__ float As[32 * 64];  // [k][i]
    __shared__ float Bs[32 * 64];  // [k][n]
    float acc[4][4] = {};
    for (int kt = 0; kt < 33; ++kt) {
#pragma unroll
        for (int q = 0; q < 2; ++q) {
            int L = tid * 2 + q;
            int il = L >> 3, kb = (L & 7) * 4;
            if (kt < 32) {
                float4 av = *(const float4*)(feats + (i0 + il) * 1024 + kt * 32 + kb);
                As[(kb + 0) * 64 + il] = av.x; As[(kb + 1) * 64 + il] = av.y;
                As[(kb + 2) * 64 + il] = av.z; As[(kb + 3) * 64 + il] = av.w;
            } else {
                float4 bx = *(const float4*)(boxesf + (i0 + il) * 4);
                float b0 = bx.x / 800.f, b1 = bx.y / 800.f;
                float b2 = bx.z / 800.f, b3 = bx.w / 800.f;
                float vals[4] = { b0, b1, b2 - b0, b3 - b1 };
#pragma unroll
                for (int x = 0; x < 4; ++x) {
                    int kg = kb + x;
                    As[(kb + x) * 64 + il] = (kg < 4) ? vals[kg] : 0.f;
                }
            }
            int kl = L >> 4, nb = (L & 15) * 4;
            int kgl = kt * 32 + kl;
            float4 bv;
            if (kgl < 1028) bv = *(const float4*)(Wg + kgl * 1024 + n0 + nb);
            else bv = make_float4(0.f, 0.f, 0.f, 0.f);
            *(float4*)(Bs + kl * 64 + nb) = bv;
        }
        __syncthreads();
#pragma unroll
        for (int k = 0; k < 32; ++k) {
            float4 a4 = *(const float4*)(As + k * 64 + ty * 4);
            float4 b4 = *(const float4*)(Bs + k * 64 + tx * 4);
            acc[0][0] = fmaf(a4.x, b4.x, acc[0][0]); acc[0][1] = fmaf(a4.x, b4.y, acc[0][1]);
            acc[0][2] = fmaf(a4.x, b4.z, acc[0][2]); acc[0][3] = fmaf(a4.x, b4.w, acc[0][3]);
            acc[1][0] = fmaf(a4.y, b4.x, acc[1][0]); acc[1][1] = fmaf(a4.y, b4.y, acc[1][1]);
            acc[1][2] = fmaf(a4.y, b4.z, acc[1][2]); acc[1][3] = fmaf(a4.y, b4.w, acc[1][3]);
            acc[2][0] = fmaf(a4.z, b4.x, acc[2][0]); acc[2][1] = fmaf(a4.z, b4.y, acc[2][1]);
            acc[2][2] = fmaf(a4.z, b4.z, acc[2][2]); acc[2][3] = fmaf(a4.z, b4.w, acc[2][3]);
            acc[3][0] = fmaf(a4.w, b4.x, acc[3][0]); acc[3][1] = fmaf(a4.w, b4.y, acc[3][1]);
            acc[3][2] = fmaf(a4.w, b4.z, acc[3][2]); acc[3][3] = fmaf(a4.w, b4.w, acc[3][3]);
        }
        __syncthreads();
    }
#pragma unroll
    for (int ii = 0; ii < 4; ++ii) {
        float4 o = make_float4(acc[ii][0], acc[ii][1], acc[ii][2], acc[ii][3]);
        *(float4*)(hX + (i0 + ty * 4 + ii) * 1024 + n0 + tx * 4) = o;
    }
}

// ---------- K7: a_s / a_d per node, per head (wave-shuffle) ----------
__global__ void k_asd1(const float* __restrict__ hX,
                       const float* __restrict__ asrcf,
                       const float* __restrict__ adstf,
                       float* __restrict__ a_s, float* __restrict__ a_d) {
    int n = blockIdx.x, tid = threadIdx.x; // 512 blocks x 256 threads
    int q = tid >> 6, lane = tid & 63;     // wave q handles head q
    float ps = 0.f, pd = 0.f;
#pragma unroll
    for (int r = 0; r < 4; ++r) {
        int col = q * 256 + r * 64 + lane;
        float v = hX[n * 1024 + col];
        ps = fmaf(v, asrcf[col], ps);
        pd = fmaf(v, adstf[col], pd);
    }
    for (int off = 32; off > 0; off >>= 1) {
        ps += __shfl_down(ps, off);
        pd += __shfl_down(pd, off);
    }
    if (lane == 0) {
        a_s[n * 4 + q] = ps;
        a_d[n * 4 + q] = pd;
    }
}

// ---------- K8: GAT1 per-dst softmax + aggregate + bias + relu ----------
__global__ void k_aggr1(const float* __restrict__ hX,
                        const float* __restrict__ a_s, const float* __restrict__ a_d,
                        const int* __restrict__ offs, const int* __restrict__ inlist,
                        const float* __restrict__ bias,
                        float* __restrict__ h1) {
    int n = blockIdx.x, t = threadIdx.x; // 512 blocks x 256 threads
    int beg = offs[n], deg = offs[n + 1] - beg;
    if (deg > 513) deg = 513;
    __shared__ int srcs[520];
    __shared__ float alpha[520][4];
    __shared__ float sm[4];
    for (int e = t; e < deg; e += 256) srcs[e] = inlist[beg + e] & 511;
    __syncthreads();
    for (int idx = t; idx < deg * 4; idx += 256) {
        int e = idx >> 2, q = idx & 3;
        float sc = a_s[srcs[e] * 4 + q] + a_d[n * 4 + q];
        alpha[e][q] = (sc >= 0.f) ? sc : 0.2f * sc;
    }
    __syncthreads();
    if (t < 4) {
        float m = -INFINITY;
        for (int e = 0; e < deg; ++e) m = fmaxf(m, alpha[e][t]);
        if (!isfinite(m)) m = 0.f;
        float s = 0.f;
        for (int e = 0; e < deg; ++e) { float ex = expf(alpha[e][t] - m); alpha[e][t] = ex; s += ex; }
        sm[t] = s + 1e-16f;
    }
    __syncthreads();
    for (int idx = t; idx < deg * 4; idx += 256) {
        int e = idx >> 2, q = idx & 3;
        alpha[e][q] /= sm[q];
    }
    __syncthreads();
    for (int q = 0; q < 4; ++q) {
        float acc = 0.f;
        for (int e = 0; e < deg; ++e) acc += alpha[e][q] * hX[srcs[e] * 1024 + q * 256 + t];
        float o = acc + bias[q * 256 + t];
        h1[n * 1024 + q * 256 + t] = fmaxf(o, 0.f);
    }
}

// ---------- K9: GAT2 GEMM + per-node a_s2 / a_d2 ----------
__global__ void k_gat2(const float* __restrict__ h1,
                       const float* __restrict__ Wf,
                       const float* __restrict__ asrcf,
                       const float* __restrict__ adstf,
                       float* __restrict__ h2, float* __restrict__ a_s2, float* __restrict__ a_d2) {
    int n = blockIdx.x, t = threadIdx.x; // 512 blocks x 128 threads
    __shared__ float xs[1024];
    __shared__ float red[128];
    for (int c = t; c < 1024; c += 128) xs[c] = h1[n * 1024 + c];
    __syncthreads();
    float acc = 0.f;
    if (t < NCLS) {
        for (int c = 0; c < 1024; ++c) acc = fmaf(xs[c], Wf[c * NCLS + t], acc);
    }
    float ps = 0.f, pd = 0.f;
    if (t < NCLS) {
        ps = acc * asrcf[t];
        pd = acc * adstf[t];
        h2[n * NCLS + t] = acc;
    }
    red[t] = (t < NCLS) ? ps : 0.f; __syncthreads();
    for (int s = 64; s > 0; s >>= 1) { if (t < s) red[t] += red[t + s]; __syncthreads(); }
    if (t == 0) a_s2[n] = red[0];
    __syncthreads();
    red[t] = (t < NCLS) ? pd : 0.f; __syncthreads();
    for (int s = 64; s > 0; s >>= 1) { if (t < s) red[t] += red[t + s]; __syncthreads(); }
    if (t == 0) a_d2[n] = red[0];
}

// ---------- K10: GAT2 aggregate -> logits + softmax probs ----------
__global__ void k_aggr2(const float* __restrict__ h2,
                        const float* __restrict__ a_s2, const float* __restrict__ a_d2,
                        const int* __restrict__ offs, const int* __restrict__ inlist,
                        const float* __restrict__ bias,
                        float* __restrict__ logits_out,
                        float* __restrict__ probs_out) {
    int n = blockIdx.x, t = threadIdx.x; // 512 blocks x 128 threads
    int beg = offs[n], deg = offs[n + 1] - beg;
    if (deg > 513) deg = 513;
    __shared__ int srcs[520];
    __shared__ float alpha[520];
    __shared__ float red[128];
    __shared__ float smden;
    for (int e = t; e < deg; e += 128) {
        int s = inlist[beg + e] & 511;
        srcs[e] = s;
        float sc = a_s2[s] + a_d2[n];
        alpha[e] = (sc >= 0.f) ? sc : 0.2f * sc;
    }
    __syncthreads();
    if (t == 0) {
        float m = -INFINITY;
        for (int e = 0; e < deg; ++e) m = fmaxf(m, alpha[e]);
        if (!isfinite(m)) m = 0.f;
        float s = 0.f;
        for (int e = 0; e < deg; ++e) { float ex = expf(alpha[e] - m); alpha[e] = ex; s += ex; }
        smden = s + 1e-16f;
    }
    __syncthreads();
    float logit = 0.f;
    if (t < NCLS) {
        float acc = 0.f;
        for (int e = 0; e < deg; ++e) acc += alpha[e] * h2[srcs[e] * NCLS + t];
        acc /= smden;
        logit = acc + bias[t];
        logits_out[n * NCLS + t] = logit;
    }
    red[t] = (t < NCLS) ? logit : -INFINITY; __syncthreads();
    for (int s = 64; s > 0; s >>= 1) { if (t < s) red[t] = fmaxf(red[t], red[t + s]); __syncthreads(); }
    float mx = red[0];
    __syncthreads();
    float ex = (t < NCLS) ? expf(logit - mx) : 0.f;
    red[t] = ex; __syncthreads();
    for (int s = 64; s > 0; s >>= 1) { if (t < s) red[t] += red[t + s]; __syncthreads(); }
    float inv = 1.f / red[0];
    if (t < NCLS) probs_out[n * NCLS + t] = ex * inv;
}

// ---------- launch ----------
extern "C" void kernel_launch(void* const* d_in, const int* in_sizes, int n_in,
                              void* d_out, int out_size, void* d_ws, size_t ws_size,
                              hipStream_t stream) {
    const float* feats   = (const float*)d_in[0];
    const float* boxes   = (const float*)d_in[1];
    const float* repn_w1 = (const float*)d_in[2];
    const float* repn_b1 = (const float*)d_in[3];
    const float* repn_w2 = (const float*)d_in[4];
    const float* repn_b2 = (const float*)d_in[5];
    const float* gat1_w    = (const float*)d_in[6];
    const float* gat1_asrc = (const float*)d_in[7];
    const float* gat1_adst = (const float*)d_in[8];
    const float* gat1_b    = (const float*)d_in[9];
    const float* gat2_w    = (const float*)d_in[10];
    const float* gat2_asrc = (const float*)d_in[11];
    const float* gat2_adst = (const float*)d_in[12];
    const float* gat2_b    = (const float*)d_in[13];
    const int* kp = (const int*)d_in[14];

    float* out = (float*)d_out;
    float* logits_out = out;                    // 512*91
    float* probs_out  = out + 512 * NCLS;       // 512*91
    float* rel_out    = out + 2 * 512 * NCLS;   // 512*512 (also read by k_topk)

    // Workspace (floats). p dead after k_rel -> h1 aliases p's region.
    float* wsf  = (float*)d_ws;
    float* hX   = wsf;                        // [0, 524288)
    float* p    = wsf + 524288;               // [524288, 786432)   512x512
    float* h1   = wsf + 524288;               // [524288, 1048576)  alias over dead p
    float* h2   = wsf + 1048576;              // 46592 (pad 47104)
    float* a_s1 = wsf + 1095680;              // 2048
    float* a_d1 = a_s1 + 2048;                // 2048
    float* a_s2 = a_d1 + 2048;                // 512
    float* a_d2 = a_s2 + 512;                 // 512 -> ends 1100800
    int* iw     = (int*)(wsf + 1100800);
    int* nbrs   = iw;                         // 4096
    int* count  = nbrs + 4096;                // 512
    int* cursor = count + 512;                // 512
    int* offs   = cursor + 512;               // 520
    int* inlist = offs + 520;                 // 4096

    hipMemsetAsync(count, 0, 1024 * sizeof(int), stream); // count+cursor

    k_p12<<<dim3(8, 8), dim3(256), 0, stream>>>(feats, repn_w1, p);
    k_rel<<<dim3(8, 32), dim3(256), 0, stream>>>(p, repn_w1, repn_b1, repn_w2,
                                                 repn_b2, boxes, rel_out);
    k_topk<<<dim3(512), dim3(64), 0, stream>>>(rel_out, kp, nbrs, count);
    k_scan<<<dim3(1), dim3(512), 0, stream>>>(count, offs);
    k_fill<<<dim3(2), dim3(256), 0, stream>>>(nbrs, kp, offs, cursor, inlist);
    k_gat1<<<dim3(16, 8), dim3(256), 0, stream>>>(feats, boxes, gat1_w, hX);
    k_asd1<<<dim3(512), dim3(256), 0, stream>>>(hX, gat1_asrc, gat1_adst, a_s1, a_d1);
    k_aggr1<<<dim3(512), dim3(256), 0, stream>>>(hX, a_s1, a_d1, offs, inlist, gat1_b, h1);
    k_gat2<<<dim3(512), dim3(128), 0, stream>>>(h1, gat2_w, gat2_asrc, gat2_adst,
                                                h2, a_s2, a_d2);
    k_aggr2<<<dim3(512), dim3(128), 0, stream>>>(h2, a_s2, a_d2, offs, inlist, gat2_b,
                                                 logits_out, probs_out);
}

// Round 5
// 250.286 us; speedup vs baseline: 1.7873x; 1.2324x over previous
//
#include <hip/hip_runtime.h>

// Inputs and outputs are float32 (established R1/R3).
#define NCLS 91
#define W1_LD 2052   // repn_w1 row length (2C+4)

// ---------- K1: p_part[z][i][r] = feats[i, z*512:+512] . Wcomb[r, z*512:+512] ----------
// Wcomb rows 0..255 = wf1, 256..511 = wf2. grid (8 r-tiles, 16 i-tiles, 2 z), 128 thr.
// Tile 32i x 64r, BK=64, 4x4 micro, reg-prefetch.
__global__ __launch_bounds__(128) void k_p12(const float* __restrict__ feats,
                                             const float* __restrict__ w1f,
                                             float* __restrict__ pp) {
    int r0 = blockIdx.x * 64, i0 = blockIdx.y * 32, z = blockIdx.z;
    int tid = threadIdx.x, tx = tid & 15, ty = tid >> 4;
    __shared__ float As[64 * 32];   // [k][i]
    __shared__ float Bs[64 * 64];   // [k][r]
    float* pout = pp + z * 262144;
    int ai = tid & 31, akq = (tid >> 5) * 16;          // A loader: 4 float4 along k
    int br = tid & 63, bkq = (tid >> 6) * 32;          // B loader: 8 float4 along k
    const float* abase = feats + (i0 + ai) * 1024 + z * 512 + akq;
    int rg = r0 + br;
    const float* bbase = w1f + (rg < 256 ? rg * W1_LD : (rg - 256) * W1_LD + 1024)
                       + z * 512 + bkq;
    float4 av[4], bv[8];
#pragma unroll
    for (int s = 0; s < 4; ++s) av[s] = *(const float4*)(abase + 4 * s);
#pragma unroll
    for (int s = 0; s < 8; ++s) bv[s] = *(const float4*)(bbase + 4 * s);
    float acc[4][4] = {};
    for (int kt = 0; kt < 8; ++kt) {
#pragma unroll
        for (int s = 0; s < 4; ++s) {   // transpose store: lanes distinct ai -> 2-way max
            int k = akq + 4 * s;
            As[(k + 0) * 32 + ai] = av[s].x; As[(k + 1) * 32 + ai] = av[s].y;
            As[(k + 2) * 32 + ai] = av[s].z; As[(k + 3) * 32 + ai] = av[s].w;
        }
#pragma unroll
        for (int s = 0; s < 8; ++s) {   // transpose store: lanes distinct br -> 2-way max
            int k = bkq + 4 * s;
            Bs[(k + 0) * 64 + br] = bv[s].x; Bs[(k + 1) * 64 + br] = bv[s].y;
            Bs[(k + 2) * 64 + br] = bv[s].z; Bs[(k + 3) * 64 + br] = bv[s].w;
        }
        __syncthreads();
        if (kt + 1 < 8) {
#pragma unroll
            for (int s = 0; s < 4; ++s) av[s] = *(const float4*)(abase + (kt + 1) * 64 + 4 * s);
#pragma unroll
            for (int s = 0; s < 8; ++s) bv[s] = *(const float4*)(bbase + (kt + 1) * 64 + 4 * s);
        }
#pragma unroll
        for (int k = 0; k < 64; ++k) {
            float4 a4 = *(const float4*)(As + k * 32 + ty * 4);
            float4 b4 = *(const float4*)(Bs + k * 64 + tx * 4);
            acc[0][0] = fmaf(a4.x, b4.x, acc[0][0]); acc[0][1] = fmaf(a4.x, b4.y, acc[0][1]);
            acc[0][2] = fmaf(a4.x, b4.z, acc[0][2]); acc[0][3] = fmaf(a4.x, b4.w, acc[0][3]);
            acc[1][0] = fmaf(a4.y, b4.x, acc[1][0]); acc[1][1] = fmaf(a4.y, b4.y, acc[1][1]);
            acc[1][2] = fmaf(a4.y, b4.z, acc[1][2]); acc[1][3] = fmaf(a4.y, b4.w, acc[1][3]);
            acc[2][0] = fmaf(a4.z, b4.x, acc[2][0]); acc[2][1] = fmaf(a4.z, b4.y, acc[2][1]);
            acc[2][2] = fmaf(a4.z, b4.z, acc[2][2]); acc[2][3] = fmaf(a4.z, b4.w, acc[2][3]);
            acc[3][0] = fmaf(a4.w, b4.x, acc[3][0]); acc[3][1] = fmaf(a4.w, b4.y, acc[3][1]);
            acc[3][2] = fmaf(a4.w, b4.z, acc[3][2]); acc[3][3] = fmaf(a4.w, b4.w, acc[3][3]);
        }
        __syncthreads();
    }
#pragma unroll
    for (int ii = 0; ii < 4; ++ii)
        *(float4*)(pout + (i0 + ty * 4 + ii) * 512 + r0 + tx * 4) =
            make_float4(acc[ii][0], acc[ii][1], acc[ii][2], acc[ii][3]);
}

// ---------- K2: rel[i][j], summing the two K-partials during staging ----------
__global__ __launch_bounds__(256) void k_rel(const float* __restrict__ pp,
                                             const float* __restrict__ w1f,
                                             const float* __restrict__ b1f,
                                             const float* __restrict__ w2f,
                                             const float* __restrict__ b2f,
                                             const float* __restrict__ boxesf,
                                             float* __restrict__ rel_out) {
    int j0 = blockIdx.x * 64, i0 = blockIdx.y * 16;
    int tid = threadIdx.x, tx = tid & 63, ty = tid >> 6;
    const float* pp0 = pp;
    const float* pp1 = pp + 262144;
    __shared__ float As1[32 * 17];  // [h][i] pad 17
    __shared__ float Bs[32 * 64];   // [h][j]
    __shared__ float Awg[32 * 4];
    __shared__ float Aw2[32];
    float4 bj = *(const float4*)(boxesf + (j0 + tx) * 4);
    float g[4][4];
#pragma unroll
    for (int s = 0; s < 4; ++s) {
        float4 bi = *(const float4*)(boxesf + (i0 + ty * 4 + s) * 4);
        g[s][0] = fabsf(bi.x - bj.x); g[s][1] = fabsf(bi.y - bj.y);
        g[s][2] = fabsf(bi.z - bj.z); g[s][3] = fabsf(bi.w - bj.w);
    }
    float acc[4] = {0.f, 0.f, 0.f, 0.f};
    int ali = tid & 15, alh = (tid >> 4) * 4;     // tid<128: one float4 along h
    int blj = tid & 63, blh = (tid >> 6) * 8;     // 2 float4 along h
    for (int ch = 0; ch < 8; ++ch) {
        int hb = ch * 32;
        if (tid < 128) {
            float4 v0 = *(const float4*)(pp0 + (i0 + ali) * 512 + hb + alh);
            float4 v1 = *(const float4*)(pp1 + (i0 + ali) * 512 + hb + alh);
            float4 b  = *(const float4*)(b1f + hb + alh);
            As1[(alh + 0) * 17 + ali] = v0.x + v1.x + b.x;
            As1[(alh + 1) * 17 + ali] = v0.y + v1.y + b.y;
            As1[(alh + 2) * 17 + ali] = v0.z + v1.z + b.z;
            As1[(alh + 3) * 17 + ali] = v0.w + v1.w + b.w;
        }
#pragma unroll
        for (int s = 0; s < 2; ++s) {
            int h = blh + 4 * s;
            float4 u0 = *(const float4*)(pp0 + (j0 + blj) * 512 + 256 + hb + h);
            float4 u1 = *(const float4*)(pp1 + (j0 + blj) * 512 + 256 + hb + h);
            Bs[(h + 0) * 64 + blj] = u0.x + u1.x;
            Bs[(h + 1) * 64 + blj] = u0.y + u1.y;
            Bs[(h + 2) * 64 + blj] = u0.z + u1.z;
            Bs[(h + 3) * 64 + blj] = u0.w + u1.w;
        }
        if (tid < 32) {
            int hg = hb + tid;
            *(float4*)(Awg + tid * 4) = *(const float4*)(w1f + hg * W1_LD + 2048);
            Aw2[tid] = w2f[hg];
        }
        __syncthreads();
#pragma unroll
        for (int hh = 0; hh < 32; ++hh) {
            float4 wg = *(const float4*)(Awg + hh * 4);
            float w2v = Aw2[hh];
            float p2v = Bs[hh * 64 + tx];
            float s0 = As1[hh * 17 + ty * 4 + 0];
            float s1 = As1[hh * 17 + ty * 4 + 1];
            float s2 = As1[hh * 17 + ty * 4 + 2];
            float s3 = As1[hh * 17 + ty * 4 + 3];
            float t0 = s0 + p2v;
            t0 = fmaf(g[0][0], wg.x, t0); t0 = fmaf(g[0][1], wg.y, t0);
            t0 = fmaf(g[0][2], wg.z, t0); t0 = fmaf(g[0][3], wg.w, t0);
            acc[0] = fmaf(w2v, fmaxf(t0, 0.f), acc[0]);
            float t1 = s1 + p2v;
            t1 = fmaf(g[1][0], wg.x, t1); t1 = fmaf(g[1][1], wg.y, t1);
            t1 = fmaf(g[1][2], wg.z, t1); t1 = fmaf(g[1][3], wg.w, t1);
            acc[1] = fmaf(w2v, fmaxf(t1, 0.f), acc[1]);
            float t2 = s2 + p2v;
            t2 = fmaf(g[2][0], wg.x, t2); t2 = fmaf(g[2][1], wg.y, t2);
            t2 = fmaf(g[2][2], wg.z, t2); t2 = fmaf(g[2][3], wg.w, t2);
            acc[2] = fmaf(w2v, fmaxf(t2, 0.f), acc[2]);
            float t3 = s3 + p2v;
            t3 = fmaf(g[3][0], wg.x, t3); t3 = fmaf(g[3][1], wg.y, t3);
            t3 = fmaf(g[3][2], wg.z, t3); t3 = fmaf(g[3][3], wg.w, t3);
            acc[3] = fmaf(w2v, fmaxf(t3, 0.f), acc[3]);
        }
        __syncthreads();
    }
    float b2v = b2f[0];
#pragma unroll
    for (int s = 0; s < 4; ++s)
        rel_out[(i0 + ty * 4 + s) * 512 + j0 + tx] = acc[s] + b2v;
}

// ---------- K3: per-row top-(k+1), drop first; count in-degrees ----------
__global__ void k_topk(const float* __restrict__ relf, const int* __restrict__ kp,
                       int* __restrict__ nbrs, int* __restrict__ count) {
    int i = blockIdx.x, lane = threadIdx.x;
    int k = *kp;
    float v[8]; int ids[8];
    for (int q = 0; q < 8; ++q) {
        int j = lane + 64 * q;
        v[q] = relf[i * 512 + j];
        ids[q] = j;
    }
    for (int pick = 0; pick < k + 1; ++pick) {
        float bv = -INFINITY; int bidx = 1 << 30;
        for (int q = 0; q < 8; ++q)
            if (v[q] > bv || (v[q] == bv && ids[q] < bidx)) { bv = v[q]; bidx = ids[q]; }
        for (int off = 32; off > 0; off >>= 1) {
            float ov = __shfl_down(bv, off);
            int oi = __shfl_down(bidx, off);
            if (ov > bv || (ov == bv && oi < bidx)) { bv = ov; bidx = oi; }
        }
        bv = __shfl(bv, 0); bidx = __shfl(bidx, 0);
        if (pick >= 1 && lane == 0) {
            nbrs[i * 8 + (pick - 1)] = bidx;
            atomicAdd(&count[bidx], 1);
        }
        for (int q = 0; q < 8; ++q) if (ids[q] == bidx) v[q] = -INFINITY;
    }
    if (lane == 0) atomicAdd(&count[i], 1);
}

// ---------- K4: exclusive scan ----------
__global__ void k_scan(const int* __restrict__ count, int* __restrict__ offs) {
    __shared__ int s[512];
    int t = threadIdx.x;
    s[t] = count[t];
    __syncthreads();
    for (int off = 1; off < 512; off <<= 1) {
        int v = (t >= off) ? s[t - off] : 0;
        __syncthreads();
        s[t] += v;
        __syncthreads();
    }
    offs[t + 1] = s[t];
    if (t == 0) offs[0] = 0;
}

// ---------- K5: fill in-edge lists ----------
__global__ void k_fill(const int* __restrict__ nbrs, const int* __restrict__ kp,
                       const int* __restrict__ offs, int* __restrict__ cursor,
                       int* __restrict__ inlist) {
    int i = blockIdx.x * blockDim.x + threadIdx.x;
    if (i >= 512) return;
    int k = *kp;
    for (int q = 0; q < k; ++q) {
        int d = nbrs[i * 8 + q] & 511;
        int pos = atomicAdd(&cursor[d], 1);
        inlist[offs[d] + pos] = i;
    }
    int pos = atomicAdd(&cursor[i], 1);
    inlist[offs[i] + pos] = i;
}

// ---------- K6: GAT1 GEMM hX=[feats|geom]@W + fused a_s1/a_d1 partials ----------
// grid (16 n-tiles, 16 i-tiles), 128 thr. Tile 32i x 64n, BK=64, geom epilogue.
__global__ __launch_bounds__(128) void k_gat1(const float* __restrict__ feats,
                                              const float* __restrict__ boxesf,
                                              const float* __restrict__ Wg,
                                              const float* __restrict__ asrcf,
                                              const float* __restrict__ adstf,
                                              float* __restrict__ hX,
                                              float* __restrict__ a_s1,
                                              float* __restrict__ a_d1) {
    int n0 = blockIdx.x * 64, i0 = blockIdx.y * 32;
    int tid = threadIdx.x, tx = tid & 15, ty = tid >> 4;
    __shared__ float As[64 * 32];   // [k][i]
    __shared__ float Bs[64 * 68];   // [k][n] pad 68 (16B-aligned, conflict-free f4 stores)
    int ai = tid & 31, akq = (tid >> 5) * 16;
    int bn4 = (tid & 15) * 4, bkl = tid >> 4;   // 8 float4: k = bkl + 8s
    const float* abase = feats + (i0 + ai) * 1024 + akq;
    const float* bbase = Wg + bkl * 1024 + n0 + bn4;
    float4 av[4], bv[8];
#pragma unroll
    for (int s = 0; s < 4; ++s) av[s] = *(const float4*)(abase + 4 * s);
#pragma unroll
    for (int s = 0; s < 8; ++s) bv[s] = *(const float4*)(bbase + (8 * s) * 1024);
    float acc[4][4] = {};
    for (int kt = 0; kt < 16; ++kt) {
#pragma unroll
        for (int s = 0; s < 4; ++s) {
            int k = akq + 4 * s;
            As[(k + 0) * 32 + ai] = av[s].x; As[(k + 1) * 32 + ai] = av[s].y;
            As[(k + 2) * 32 + ai] = av[s].z; As[(k + 3) * 32 + ai] = av[s].w;
        }
#pragma unroll
        for (int s = 0; s < 8; ++s)
            *(float4*)(Bs + (bkl + 8 * s) * 68 + bn4) = bv[s];
        __syncthreads();
        if (kt + 1 < 16) {
#pragma unroll
            for (int s = 0; s < 4; ++s)
                av[s] = *(const float4*)(abase + (kt + 1) * 64 + 4 * s);
#pragma unroll
            for (int s = 0; s < 8; ++s)
                bv[s] = *(const float4*)(bbase + ((kt + 1) * 64 + 8 * s) * 1024);
        }
#pragma unroll
        for (int k = 0; k < 64; ++k) {
            float4 a4 = *(const float4*)(As + k * 32 + ty * 4);
            float4 b4 = *(const float4*)(Bs + k * 68 + tx * 4);
            acc[0][0] = fmaf(a4.x, b4.x, acc[0][0]); acc[0][1] = fmaf(a4.x, b4.y, acc[0][1]);
            acc[0][2] = fmaf(a4.x, b4.z, acc[0][2]); acc[0][3] = fmaf(a4.x, b4.w, acc[0][3]);
            acc[1][0] = fmaf(a4.y, b4.x, acc[1][0]); acc[1][1] = fmaf(a4.y, b4.y, acc[1][1]);
            acc[1][2] = fmaf(a4.y, b4.z, acc[1][2]); acc[1][3] = fmaf(a4.y, b4.w, acc[1][3]);
            acc[2][0] = fmaf(a4.z, b4.x, acc[2][0]); acc[2][1] = fmaf(a4.z, b4.y, acc[2][1]);
            acc[2][2] = fmaf(a4.z, b4.z, acc[2][2]); acc[2][3] = fmaf(a4.z, b4.w, acc[2][3]);
            acc[3][0] = fmaf(a4.w, b4.x, acc[3][0]); acc[3][1] = fmaf(a4.w, b4.y, acc[3][1]);
            acc[3][2] = fmaf(a4.w, b4.z, acc[3][2]); acc[3][3] = fmaf(a4.w, b4.w, acc[3][3]);
        }
        __syncthreads();
    }
    // geom (K rows 1024..1027) epilogue
    float4 wg[4];
#pragma unroll
    for (int x = 0; x < 4; ++x)
        wg[x] = *(const float4*)(Wg + (1024 + x) * 1024 + n0 + tx * 4);
#pragma unroll
    for (int ii = 0; ii < 4; ++ii) {
        float4 bx = *(const float4*)(boxesf + (i0 + ty * 4 + ii) * 4);
        float g0 = bx.x / 800.f, g1 = bx.y / 800.f;
        float g2 = bx.z / 800.f - g0, g3 = bx.w / 800.f - g1;
        acc[ii][0] += g0 * wg[0].x + g1 * wg[1].x + g2 * wg[2].x + g3 * wg[3].x;
        acc[ii][1] += g0 * wg[0].y + g1 * wg[1].y + g2 * wg[2].y + g3 * wg[3].y;
        acc[ii][2] += g0 * wg[0].z + g1 * wg[1].z + g2 * wg[2].z + g3 * wg[3].z;
        acc[ii][3] += g0 * wg[0].w + g1 * wg[1].w + g2 * wg[2].w + g3 * wg[3].w;
        *(float4*)(hX + (i0 + ty * 4 + ii) * 1024 + n0 + tx * 4) =
            make_float4(acc[ii][0], acc[ii][1], acc[ii][2], acc[ii][3]);
    }
    // fused a_s / a_d partials (head q = n0/256)
    float4 as4 = *(const float4*)(asrcf + n0 + tx * 4);
    float4 ad4 = *(const float4*)(adstf + n0 + tx * 4);
    int q = n0 >> 8;
#pragma unroll
    for (int ii = 0; ii < 4; ++ii) {
        float ps = acc[ii][0] * as4.x + acc[ii][1] * as4.y
                 + acc[ii][2] * as4.z + acc[ii][3] * as4.w;
        float pd = acc[ii][0] * ad4.x + acc[ii][1] * ad4.y
                 + acc[ii][2] * ad4.z + acc[ii][3] * ad4.w;
#pragma unroll
        for (int off = 8; off > 0; off >>= 1) {
            ps += __shfl_down(ps, off, 16);
            pd += __shfl_down(pd, off, 16);
        }
        if (tx == 0) {
            atomicAdd(&a_s1[(i0 + ty * 4 + ii) * 4 + q], ps);
            atomicAdd(&a_d1[(i0 + ty * 4 + ii) * 4 + q], pd);
        }
    }
}

// ---------- K8: GAT1 per-dst softmax + aggregate + bias + relu ----------
__global__ void k_aggr1(const float* __restrict__ hX,
                        const float* __restrict__ a_s, const float* __restrict__ a_d,
                        const int* __restrict__ offs, const int* __restrict__ inlist,
                        const float* __restrict__ bias,
                        float* __restrict__ h1) {
    int n = blockIdx.x, t = threadIdx.x;
    int beg = offs[n], deg = offs[n + 1] - beg;
    if (deg > 513) deg = 513;
    __shared__ int srcs[520];
    __shared__ float alpha[520][4];
    __shared__ float sm[4];
    for (int e = t; e < deg; e += 256) srcs[e] = inlist[beg + e] & 511;
    __syncthreads();
    for (int idx = t; idx < deg * 4; idx += 256) {
        int e = idx >> 2, q = idx & 3;
        float sc = a_s[srcs[e] * 4 + q] + a_d[n * 4 + q];
        alpha[e][q] = (sc >= 0.f) ? sc : 0.2f * sc;
    }
    __syncthreads();
    if (t < 4) {
        float m = -INFINITY;
        for (int e = 0; e < deg; ++e) m = fmaxf(m, alpha[e][t]);
        if (!isfinite(m)) m = 0.f;
        float s = 0.f;
        for (int e = 0; e < deg; ++e) { float ex = expf(alpha[e][t] - m); alpha[e][t] = ex; s += ex; }
        sm[t] = s + 1e-16f;
    }
    __syncthreads();
    for (int idx = t; idx < deg * 4; idx += 256) {
        int e = idx >> 2, q = idx & 3;
        alpha[e][q] /= sm[q];
    }
    __syncthreads();
    for (int q = 0; q < 4; ++q) {
        float acc = 0.f;
        for (int e = 0; e < deg; ++e) acc += alpha[e][q] * hX[srcs[e] * 1024 + q * 256 + t];
        h1[n * 1024 + q * 256 + t] = fmaxf(acc + bias[q * 256 + t], 0.f);
    }
}

// ---------- K9: GAT2 GEMM + a_s2/a_d2 (2-way K-split, 4 accums) ----------
__global__ __launch_bounds__(256) void k_gat2(const float* __restrict__ h1,
                                              const float* __restrict__ Wf,
                                              const float* __restrict__ asrcf,
                                              const float* __restrict__ adstf,
                                              float* __restrict__ h2,
                                              float* __restrict__ a_s2,
                                              float* __restrict__ a_d2) {
    int n = blockIdx.x, t = threadIdx.x;
    __shared__ float xs[1024];
    __shared__ float hbuf[NCLS];
    __shared__ float sred[256], dred[256];
    for (int c = t; c < 1024; c += 256) xs[c] = h1[n * 1024 + c];
    __syncthreads();
    int cls = t & 127, kh = t >> 7;
    float acc = 0.f;
    if (cls < NCLS) {
        const float* wp = Wf + (kh * 512) * NCLS + cls;
        const float* xp = xs + kh * 512;
        float a0 = 0.f, a1 = 0.f, a2 = 0.f, a3 = 0.f;
        for (int c = 0; c < 512; c += 4) {
            a0 = fmaf(xp[c + 0], wp[(c + 0) * NCLS], a0);
            a1 = fmaf(xp[c + 1], wp[(c + 1) * NCLS], a1);
            a2 = fmaf(xp[c + 2], wp[(c + 2) * NCLS], a2);
            a3 = fmaf(xp[c + 3], wp[(c + 3) * NCLS], a3);
        }
        acc = (a0 + a1) + (a2 + a3);
    }
    if (kh == 0 && cls < NCLS) hbuf[cls] = acc;
    __syncthreads();
    float tot = 0.f;
    int act = (kh == 1 && cls < NCLS);
    if (act) { tot = acc + hbuf[cls]; h2[n * NCLS + cls] = tot; }
    sred[t] = act ? tot * asrcf[cls] : 0.f;
    dred[t] = act ? tot * adstf[cls] : 0.f;
    __syncthreads();
    for (int s = 128; s > 0; s >>= 1) {
        if (t < s) { sred[t] += sred[t + s]; dred[t] += dred[t + s]; }
        __syncthreads();
    }
    if (t == 0) { a_s2[n] = sred[0]; a_d2[n] = dred[0]; }
}

// ---------- K10: GAT2 aggregate -> logits + softmax probs ----------
__global__ void k_aggr2(const float* __restrict__ h2,
                        const float* __restrict__ a_s2, const float* __restrict__ a_d2,
                        const int* __restrict__ offs, const int* __restrict__ inlist,
                        const float* __restrict__ bias,
                        float* __restrict__ logits_out,
                        float* __restrict__ probs_out) {
    int n = blockIdx.x, t = threadIdx.x;
    int beg = offs[n], deg = offs[n + 1] - beg;
    if (deg > 513) deg = 513;
    __shared__ int srcs[520];
    __shared__ float alpha[520];
    __shared__ float red[128];
    __shared__ float smden;
    for (int e = t; e < deg; e += 128) {
        int s = inlist[beg + e] & 511;
        srcs[e] = s;
        float sc = a_s2[s] + a_d2[n];
        alpha[e] = (sc >= 0.f) ? sc : 0.2f * sc;
    }
    __syncthreads();
    if (t == 0) {
        float m = -INFINITY;
        for (int e = 0; e < deg; ++e) m = fmaxf(m, alpha[e]);
        if (!isfinite(m)) m = 0.f;
        float s = 0.f;
        for (int e = 0; e < deg; ++e) { float ex = expf(alpha[e] - m); alpha[e] = ex; s += ex; }
        smden = s + 1e-16f;
    }
    __syncthreads();
    float logit = 0.f;
    if (t < NCLS) {
        float acc = 0.f;
        for (int e = 0; e < deg; ++e) acc += alpha[e] * h2[srcs[e] * NCLS + t];
        logit = acc / smden + bias[t];
        logits_out[n * NCLS + t] = logit;
    }
    red[t] = (t < NCLS) ? logit : -INFINITY; __syncthreads();
    for (int s = 64; s > 0; s >>= 1) { if (t < s) red[t] = fmaxf(red[t], red[t + s]); __syncthreads(); }
    float mx = red[0];
    __syncthreads();
    float ex = (t < NCLS) ? expf(logit - mx) : 0.f;
    red[t] = ex; __syncthreads();
    for (int s = 64; s > 0; s >>= 1) { if (t < s) red[t] += red[t + s]; __syncthreads(); }
    float inv = 1.f / red[0];
    if (t < NCLS) probs_out[n * NCLS + t] = ex * inv;
}

// ---------- launch ----------
extern "C" void kernel_launch(void* const* d_in, const int* in_sizes, int n_in,
                              void* d_out, int out_size, void* d_ws, size_t ws_size,
                              hipStream_t stream) {
    const float* feats   = (const float*)d_in[0];
    const float* boxes   = (const float*)d_in[1];
    const float* repn_w1 = (const float*)d_in[2];
    const float* repn_b1 = (const float*)d_in[3];
    const float* repn_w2 = (const float*)d_in[4];
    const float* repn_b2 = (const float*)d_in[5];
    const float* gat1_w    = (const float*)d_in[6];
    const float* gat1_asrc = (const float*)d_in[7];
    const float* gat1_adst = (const float*)d_in[8];
    const float* gat1_b    = (const float*)d_in[9];
    const float* gat2_w    = (const float*)d_in[10];
    const float* gat2_asrc = (const float*)d_in[11];
    const float* gat2_adst = (const float*)d_in[12];
    const float* gat2_b    = (const float*)d_in[13];
    const int* kp = (const int*)d_in[14];

    float* out = (float*)d_out;
    float* logits_out = out;
    float* probs_out  = out + 512 * NCLS;
    float* rel_out    = out + 2 * 512 * NCLS;

    float* wsf  = (float*)d_ws;
    float* hX   = wsf;                 // [0, 524288)
    float* pp   = wsf + 524288;        // two 512x512 partials, [524288, 1048576)
    float* h1   = wsf + 524288;        // alias (pp dead after k_rel)
    float* h2   = wsf + 1048576;       // 46592, pad to 47104
    float* a_s2 = wsf + 1095680;       // 512
    float* a_d2 = wsf + 1096192;       // 512
    float* a_s1 = wsf + 1096704;       // 2048 (zeroed)
    float* a_d1 = wsf + 1098752;       // 2048 (zeroed)
    int* ib     = (int*)(wsf + 1100800);
    int* count  = ib;                  // 512 (zeroed)
    int* cursor = ib + 512;            // 512 (zeroed)
    int* nbrs   = ib + 1024;           // 4096
    int* offs   = ib + 5120;           // 520
    int* inlist = ib + 5640;           // 4096

    // zero a_s1 + a_d1 + count + cursor (contiguous 5120 x 4B)
    hipMemsetAsync(a_s1, 0, 20480, stream);

    k_p12<<<dim3(8, 16, 2), dim3(128), 0, stream>>>(feats, repn_w1, pp);
    k_rel<<<dim3(8, 32), dim3(256), 0, stream>>>(pp, repn_w1, repn_b1, repn_w2,
                                                 repn_b2, boxes, rel_out);
    k_topk<<<dim3(512), dim3(64), 0, stream>>>(rel_out, kp, nbrs, count);
    k_scan<<<dim3(1), dim3(512), 0, stream>>>(count, offs);
    k_fill<<<dim3(2), dim3(256), 0, stream>>>(nbrs, kp, offs, cursor, inlist);
    k_gat1<<<dim3(16, 16), dim3(128), 0, stream>>>(feats, boxes, gat1_w,
                                                   gat1_asrc, gat1_adst,
                                                   hX, a_s1, a_d1);
    k_aggr1<<<dim3(512), dim3(256), 0, stream>>>(hX, a_s1, a_d1, offs, inlist, gat1_b, h1);
    k_gat2<<<dim3(512), dim3(256), 0, stream>>>(h1, gat2_w, gat2_asrc, gat2_adst,
                                                h2, a_s2, a_d2);
    k_aggr2<<<dim3(512), dim3(128), 0, stream>>>(h2, a_s2, a_d2, offs, inlist, gat2_b,
                                                 logits_out, probs_out);
}